// Round 1
// baseline (1845.335 us; speedup 1.0000x reference)
//
#include <hip/hip_runtime.h>

#define T_ 4
#define B_ 64
#define D_ 512
#define V_ 256
#define BDV (B_*D_*V_)     // 8388608
#define TBDV (T_*BDV)      // 33554432

// ---------------------------------------------------------------------------
// Kernel 1: Yq = bn_q(Wq @ x), Yk = bn_k(Wk @ x), batched over (t,b).
// Block: 256 threads, computes a 64(o) x 64(v) tile of BOTH outputs for one
// batch bt. Shared A-tile read once for both weight matrices.
// ---------------------------------------------------------------------------
__global__ __launch_bounds__(256) void k_qk_gemm(
    const float* __restrict__ x,
    const float* __restrict__ Wq, const float* __restrict__ Wk,
    const float* __restrict__ qg, const float* __restrict__ qb,
    const float* __restrict__ qm, const float* __restrict__ qv,
    const float* __restrict__ kg, const float* __restrict__ kb,
    const float* __restrict__ km, const float* __restrict__ kv,
    float* __restrict__ Yq, float* __restrict__ Yk)
{
    __shared__ float As[16][64];     // [kk][v']
    __shared__ float Wsq[16][64];    // [kk][o'] (transposed stage)
    __shared__ float Wsk[16][64];

    const int tid = threadIdx.x;
    const int tx = tid & 15;         // v quad
    const int ty = tid >> 4;         // o quad
    const int bt = blockIdx.z;       // t*B + b
    const int o0 = blockIdx.y * 64;
    const int v0 = blockIdx.x * 64;

    const float* A = x + (size_t)bt * (D_ * V_);

    float accq[4][4], acck[4][4];
#pragma unroll
    for (int i = 0; i < 4; ++i)
#pragma unroll
        for (int j = 0; j < 4; ++j) { accq[i][j] = 0.f; acck[i][j] = 0.f; }

    const int arow = tid >> 4;            // 0..15 (k within chunk)
    const int acol = (tid & 15) * 4;      // 0..60 (v within tile)
    const int wrow = tid >> 2;            // 0..63 (o within tile)
    const int wcol = (tid & 3) * 4;       // 0..12 (k within chunk)

    for (int k0 = 0; k0 < D_; k0 += 16) {
        float4 a4  = *(const float4*)&A[(size_t)(k0 + arow) * V_ + v0 + acol];
        float4 wq4 = *(const float4*)&Wq[(size_t)(o0 + wrow) * D_ + k0 + wcol];
        float4 wk4 = *(const float4*)&Wk[(size_t)(o0 + wrow) * D_ + k0 + wcol];

        *(float4*)&As[arow][acol] = a4;
        Wsq[wcol + 0][wrow] = wq4.x; Wsq[wcol + 1][wrow] = wq4.y;
        Wsq[wcol + 2][wrow] = wq4.z; Wsq[wcol + 3][wrow] = wq4.w;
        Wsk[wcol + 0][wrow] = wk4.x; Wsk[wcol + 1][wrow] = wk4.y;
        Wsk[wcol + 2][wrow] = wk4.z; Wsk[wcol + 3][wrow] = wk4.w;
        __syncthreads();

#pragma unroll
        for (int kk = 0; kk < 16; ++kk) {
            float4 av = *(const float4*)&As[kk][tx * 4];
            float4 wq = *(const float4*)&Wsq[kk][ty * 4];
            float4 wk = *(const float4*)&Wsk[kk][ty * 4];
            float aj[4]  = { av.x, av.y, av.z, av.w };
            float wqi[4] = { wq.x, wq.y, wq.z, wq.w };
            float wki[4] = { wk.x, wk.y, wk.z, wk.w };
#pragma unroll
            for (int i = 0; i < 4; ++i)
#pragma unroll
                for (int j = 0; j < 4; ++j) {
                    accq[i][j] += wqi[i] * aj[j];
                    acck[i][j] += wki[i] * aj[j];
                }
        }
        __syncthreads();
    }

    const size_t obase = (size_t)bt * (D_ * V_);
#pragma unroll
    for (int i = 0; i < 4; ++i) {
        const int o = o0 + ty * 4 + i;
        const float invq = qg[o] * (1.0f / sqrtf(qv[o] + 1e-5f));
        const float addq = qb[o] - qm[o] * invq;
        const float invk = kg[o] * (1.0f / sqrtf(kv[o] + 1e-5f));
        const float addk = kb[o] - km[o] * invk;
        float4 rq, rk;
        rq.x = accq[i][0] * invq + addq; rq.y = accq[i][1] * invq + addq;
        rq.z = accq[i][2] * invq + addq; rq.w = accq[i][3] * invq + addq;
        rk.x = acck[i][0] * invk + addk; rk.y = acck[i][1] * invk + addk;
        rk.z = acck[i][2] * invk + addk; rk.w = acck[i][3] * invk + addk;
        *(float4*)&Yq[obase + (size_t)o * V_ + v0 + tx * 4] = rq;
        *(float4*)&Yk[obase + (size_t)o * V_ + v0 + tx * 4] = rk;
    }
}

// ---------------------------------------------------------------------------
// Kernel 2: LIF(q), LIF(k), q_sum over head-dim, gate = LIF(q_sum, 0.5),
// out = gate * k_spikes  (binary, written as f32).
// Block: one (b,h) pair, 1024 threads = 4 d-quarters x 256 v. outb may alias
// Yq: every element is read and written by the same thread, reads first.
// ---------------------------------------------------------------------------
__global__ __launch_bounds__(1024) void k_lif_gate(
    const float* __restrict__ Yq, const float* __restrict__ Yk,
    float* __restrict__ outb)
{
    __shared__ float red[4][4][256];  // [dq][t][v]

    const int tid = threadIdx.x;
    const int v  = tid & 255;
    const int dq = tid >> 8;          // 0..3
    const int b  = blockIdx.x >> 2;
    const int h  = blockIdx.x & 3;
    const int c0 = h * 128 + dq * 32;

    float qsum[4] = {0.f, 0.f, 0.f, 0.f};
    unsigned kbits[4] = {0u, 0u, 0u, 0u};

#pragma unroll 4
    for (int dd = 0; dd < 32; ++dd) {
        const int base = (b * D_ + c0 + dd) * V_ + v;
        float vq = 0.f, vk = 0.f;
#pragma unroll
        for (int t = 0; t < 4; ++t) {
            const float yq = Yq[t * BDV + base];
            vq += (yq - vq) * 0.5f;
            if (vq >= 1.0f) { qsum[t] += 1.0f; vq = 0.f; }
            const float yk = Yk[t * BDV + base];
            vk += (yk - vk) * 0.5f;
            if (vk >= 1.0f) { kbits[t] |= (1u << dd); vk = 0.f; }
        }
    }

#pragma unroll
    for (int t = 0; t < 4; ++t) red[dq][t][v] = qsum[t];
    __syncthreads();

    float g = 0.f;
    float gate[4];
#pragma unroll
    for (int t = 0; t < 4; ++t) {
        const float qs = red[0][t][v] + red[1][t][v] + red[2][t][v] + red[3][t][v];
        g += (qs - g) * 0.5f;
        if (g >= 0.5f) { gate[t] = 1.f; g = 0.f; } else gate[t] = 0.f;
    }

#pragma unroll 4
    for (int dd = 0; dd < 32; ++dd) {
        const int base = (b * D_ + c0 + dd) * V_ + v;
#pragma unroll
        for (int t = 0; t < 4; ++t) {
            outb[t * BDV + base] =
                (gate[t] != 0.f && ((kbits[t] >> dd) & 1u)) ? 1.f : 0.f;
        }
    }
}

// ---------------------------------------------------------------------------
// Kernel 3: out2 = LIF(bn_p(Wp @ out)). Each block computes a 64x64 (o,v)
// tile for ALL 4 time steps of one b, then runs the LIF scan in registers and
// writes final spikes directly (no Yp materialization).
// ---------------------------------------------------------------------------
__global__ __launch_bounds__(256) void k_p_gemm_lif(
    const float* __restrict__ outb, const float* __restrict__ Wp,
    const float* __restrict__ pg, const float* __restrict__ pb,
    const float* __restrict__ pm, const float* __restrict__ pv,
    float* __restrict__ out2)
{
    __shared__ float As[4][16][64];   // [t][kk][v']
    __shared__ float Ws[16][64];      // [kk][o']

    const int tid = threadIdx.x;
    const int tx = tid & 15;
    const int ty = tid >> 4;
    const int b  = blockIdx.z;
    const int o0 = blockIdx.y * 64;
    const int v0 = blockIdx.x * 64;

    float acc[4][4][4];   // [t][i][j]
#pragma unroll
    for (int t = 0; t < 4; ++t)
#pragma unroll
        for (int i = 0; i < 4; ++i)
#pragma unroll
            for (int j = 0; j < 4; ++j) acc[t][i][j] = 0.f;

    const int arow = tid >> 4;
    const int acol = (tid & 15) * 4;
    const int wrow = tid >> 2;
    const int wcol = (tid & 3) * 4;

    for (int k0 = 0; k0 < D_; k0 += 16) {
        float4 w4 = *(const float4*)&Wp[(size_t)(o0 + wrow) * D_ + k0 + wcol];
        float4 a4[4];
#pragma unroll
        for (int t = 0; t < 4; ++t)
            a4[t] = *(const float4*)&outb[(size_t)t * BDV +
                                          (size_t)(b * D_ + k0 + arow) * V_ + v0 + acol];

        Ws[wcol + 0][wrow] = w4.x; Ws[wcol + 1][wrow] = w4.y;
        Ws[wcol + 2][wrow] = w4.z; Ws[wcol + 3][wrow] = w4.w;
#pragma unroll
        for (int t = 0; t < 4; ++t)
            *(float4*)&As[t][arow][acol] = a4[t];
        __syncthreads();

#pragma unroll
        for (int kk = 0; kk < 16; ++kk) {
            float4 w = *(const float4*)&Ws[kk][ty * 4];
            float wi[4] = { w.x, w.y, w.z, w.w };
#pragma unroll
            for (int t = 0; t < 4; ++t) {
                float4 av = *(const float4*)&As[t][kk][tx * 4];
                float aj[4] = { av.x, av.y, av.z, av.w };
#pragma unroll
                for (int i = 0; i < 4; ++i)
#pragma unroll
                    for (int j = 0; j < 4; ++j)
                        acc[t][i][j] += wi[i] * aj[j];
            }
        }
        __syncthreads();
    }

#pragma unroll
    for (int i = 0; i < 4; ++i) {
        const int o = o0 + ty * 4 + i;
        const float inv = pg[o] * (1.0f / sqrtf(pv[o] + 1e-5f));
        const float add = pb[o] - pm[o] * inv;
        float vs[4] = {0.f, 0.f, 0.f, 0.f};
#pragma unroll
        for (int t = 0; t < 4; ++t) {
            float r[4];
#pragma unroll
            for (int j = 0; j < 4; ++j) {
                const float y = acc[t][i][j] * inv + add;
                vs[j] += (y - vs[j]) * 0.5f;
                if (vs[j] >= 1.0f) { r[j] = 1.f; vs[j] = 0.f; } else r[j] = 0.f;
            }
            float4 r4; r4.x = r[0]; r4.y = r[1]; r4.z = r[2]; r4.w = r[3];
            *(float4*)&out2[(size_t)((t * B_ + b) * D_ + o) * V_ + v0 + tx * 4] = r4;
        }
    }
}

// ---------------------------------------------------------------------------
extern "C" void kernel_launch(void* const* d_in, const int* in_sizes, int n_in,
                              void* d_out, int out_size, void* d_ws, size_t ws_size,
                              hipStream_t stream)
{
    const float* x  = (const float*)d_in[0];
    const float* Wq = (const float*)d_in[1];
    const float* qg = (const float*)d_in[2];
    const float* qb = (const float*)d_in[3];
    const float* qm = (const float*)d_in[4];
    const float* qv = (const float*)d_in[5];
    const float* Wk = (const float*)d_in[6];
    const float* kg = (const float*)d_in[7];
    const float* kb = (const float*)d_in[8];
    const float* km = (const float*)d_in[9];
    const float* kv = (const float*)d_in[10];
    const float* Wp = (const float*)d_in[11];
    const float* pg = (const float*)d_in[12];
    const float* pb = (const float*)d_in[13];
    const float* pm = (const float*)d_in[14];
    const float* pv = (const float*)d_in[15];

    float* Yq   = (float*)d_ws;
    float* Yk   = Yq + (size_t)TBDV;
    float* outb = Yq;              // alias: safe, same-thread read-then-write
    float* out2 = (float*)d_out;

    dim3 g1(4, 8, 256);            // v-tiles, o-tiles, t*B batches
    k_qk_gemm<<<g1, 256, 0, stream>>>(x, Wq, Wk, qg, qb, qm, qv,
                                      kg, kb, km, kv, Yq, Yk);

    k_lif_gate<<<256, 1024, 0, stream>>>(Yq, Yk, outb);

    dim3 g3(4, 8, 64);             // v-tiles, o-tiles, b batches
    k_p_gemm_lif<<<g3, 256, 0, stream>>>(outb, Wp, pg, pb, pm, pv, out2);
}

// Round 2
// 987.341 us; speedup vs baseline: 1.8690x; 1.8690x over previous
//
#include <hip/hip_runtime.h>

#define T_ 4
#define B_ 64
#define D_ 512
#define V_ 256
#define BDV  (8388608ull)      // B*D*V
#define TBDV (33554432ull)     // T*B*D*V

// ---- workspace byte offsets (total ~474.5 MB) ----
#define XSH   0ull             // x^T split hi   (t,b,v,d) bf16  67.1 MB
#define XSM   67108864ull      // x^T split mid
#define XSL   134217728ull     // x^T split lo ; later reused as OUTBT
#define OUTBT XSL              // gate*k spikes, (t,b,v,d) bf16 {0,1}
#define YPOFF 0ull             // Yp fp32 (aliases XSH/XSM region, xs dead by then)
#define YQOFF 201326592ull     // bn(Wq@x) fp32 (t,b,d,v) 134.2 MB
#define YKOFF 335544320ull     // bn(Wk@x) fp32
#define WSPL  469762048ull     // 9 W-splits bf16: [wq h,m,l][wk h,m,l][wp h,m,l] x 512KB
#define BNOF  474480640ull     // 6x512 floats: invq,addq,invk,addk,invp,addp

typedef unsigned short u16;
typedef __attribute__((ext_vector_type(8))) __bf16 bf16x8;
typedef __attribute__((ext_vector_type(4))) float f32x4;
typedef __attribute__((ext_vector_type(8))) unsigned short u16x8;

// exact RNE fp32 -> bf16 (bit twiddle; deterministic)
__device__ __forceinline__ u16 f2bf(float f) {
    unsigned u = __float_as_uint(f);
    return (u16)((u + 0x7FFFu + ((u >> 16) & 1u)) >> 16);
}
__device__ __forceinline__ float bf2f(u16 h) {
    return __uint_as_float(((unsigned)h) << 16);
}

// async global->LDS, 16B per lane; LDS dest = wave-uniform base + lane*16
__device__ __forceinline__ void gld_lds16(const void* g, void* l) {
    __builtin_amdgcn_global_load_lds(
        (const __attribute__((address_space(1))) unsigned int*)(unsigned long long)g,
        (__attribute__((address_space(3))) unsigned int*)(unsigned long long)l,
        16, 0, 0);
}

// ---------------------------------------------------------------------------
// prep: 3-way bf16 split of Wq/Wk/Wp (o,d layout) + BN constants
// ---------------------------------------------------------------------------
__global__ __launch_bounds__(256) void k_prep(
    const float* __restrict__ Wq, const float* __restrict__ Wk, const float* __restrict__ Wp,
    const float* __restrict__ qg, const float* __restrict__ qb,
    const float* __restrict__ qm, const float* __restrict__ qv,
    const float* __restrict__ kg, const float* __restrict__ kb,
    const float* __restrict__ km, const float* __restrict__ kv,
    const float* __restrict__ pg, const float* __restrict__ pb,
    const float* __restrict__ pm, const float* __restrict__ pv,
    char* __restrict__ ws)
{
    const int g = blockIdx.x * 256 + threadIdx.x;     // 0..262143
    u16* base = (u16*)(ws + WSPL);
    const float* W0 = Wq; const float* W1 = Wk; const float* W2 = Wp;
#pragma unroll
    for (int mat = 0; mat < 3; ++mat) {
        const float f = (mat == 0 ? W0 : (mat == 1 ? W1 : W2))[g];
        const u16 h = f2bf(f);            const float fh = bf2f(h);
        const u16 m = f2bf(f - fh);       const float fm = bf2f(m);
        const u16 l = f2bf(f - fh - fm);
        base[(size_t)(mat * 3 + 0) * 262144 + g] = h;
        base[(size_t)(mat * 3 + 1) * 262144 + g] = m;
        base[(size_t)(mat * 3 + 2) * 262144 + g] = l;
    }
    if (g < 512) {
        float* bn = (float*)(ws + BNOF);
        float iv;
        iv = qg[g] * (1.0f / sqrtf(qv[g] + 1e-5f)); bn[g]        = iv; bn[512  + g] = qb[g] - qm[g] * iv;
        iv = kg[g] * (1.0f / sqrtf(kv[g] + 1e-5f)); bn[1024 + g] = iv; bn[1536 + g] = kb[g] - km[g] * iv;
        iv = pg[g] * (1.0f / sqrtf(pv[g] + 1e-5f)); bn[2048 + g] = iv; bn[2560 + g] = pb[g] - pm[g] * iv;
    }
}

// ---------------------------------------------------------------------------
// split_x: x (t,b,d,v) fp32 -> transposed 3-way bf16 splits (t,b,v,d)
// 64x64 tile transpose via LDS (+1 pad)
// ---------------------------------------------------------------------------
__global__ __launch_bounds__(256) void k_split_x(
    const float* __restrict__ x,
    u16* __restrict__ xh, u16* __restrict__ xm, u16* __restrict__ xl)
{
    __shared__ float tile[64][65];
    const int bt = blockIdx.z;
    const int d0 = blockIdx.y * 64;
    const int v0 = blockIdx.x * 64;
    const int c  = threadIdx.x & 63;
    const int r4 = threadIdx.x >> 6;

    const float* src = x + ((size_t)bt * D_ + d0) * V_ + v0;
#pragma unroll
    for (int i = 0; i < 16; ++i) {
        const int row = i * 4 + r4;               // d within tile
        tile[row][c] = src[(size_t)row * V_ + c];
    }
    __syncthreads();
#pragma unroll
    for (int i = 0; i < 16; ++i) {
        const int vr = i * 4 + r4;                // v within tile
        const float f = tile[c][vr];              // transpose read, conflict-free
        const u16 h = f2bf(f);            const float fh = bf2f(h);
        const u16 m = f2bf(f - fh);       const float fm = bf2f(m);
        const u16 l = f2bf(f - fh - fm);
        const size_t o = ((size_t)bt * V_ + v0 + vr) * D_ + d0 + c;
        xh[o] = h; xm[o] = m; xl[o] = l;
    }
}

// ---------------------------------------------------------------------------
// k_gemm<NB,NP>: Y[bt][o][v] = bn( W @ X ) with bf16-split emulation.
//   A-operand = W splits (o,d) at ws+a0/a1/a2 ; B-operand = X^T rows (bt,v,d)
//   at ws+b0.. (NB splits). NP passes over split products.
// 128x128 tile, BK=32, 4 waves (2x2 of 64x64), mfma_f32_16x16x32_bf16.
// LDS: 1KB chunks, frag-ordered (lane-linear) -> conflict-free ds_read_b128.
// ---------------------------------------------------------------------------
template<int NB, int NP>
__global__ __launch_bounds__(256, 2) void k_gemm(
    const char* __restrict__ ws,
    unsigned b0, unsigned b1, unsigned b2,
    unsigned a0, unsigned a1, unsigned a2,
    unsigned bnoff, unsigned coff)
{
    constexpr int NARR = NB + 3;                 // B-split arrays + 3 A-splits
    extern __shared__ u16 smem[];                // NARR*8 KB

    const int tid  = threadIdx.x;
    const int lane = tid & 63;
    const int wave = tid >> 6;
    const int wr = wave >> 1, wc = wave & 1;
    const int bt = blockIdx.z;
    const int o0 = blockIdx.y * 128;
    const int v0 = blockIdx.x * 128;

    // per-lane global byte offsets (into ws) for staging
    unsigned gb[NARR];
    {
        const unsigned kcol = (unsigned)(lane >> 4) * 8u;
        const unsigned rb = ((unsigned)bt * 256u + (unsigned)v0 + (unsigned)(lane & 15)) * 512u + kcol;
        const unsigned ra = ((unsigned)(o0 + (lane & 15))) * 512u + kcol;
        const unsigned barr[3] = {b0, b1, b2};
#pragma unroll
        for (int s = 0; s < NB; ++s) gb[s] = barr[s] + rb * 2u;
        const unsigned aarr[3] = {a0, a1, a2};
#pragma unroll
        for (int s = 0; s < 3; ++s) gb[NB + s] = aarr[s] + ra * 2u;
    }

    f32x4 acc[4][4];
#pragma unroll
    for (int i = 0; i < 4; ++i)
#pragma unroll
        for (int j = 0; j < 4; ++j) acc[i][j] = (f32x4){0.f, 0.f, 0.f, 0.f};

    constexpr int PAv[6] = {0, 0, 1, 1, 0, 2};
    constexpr int PBv[6] = {0, 1, 0, 1, 2, 0};

    for (int it = 0; it < 16; ++it) {
        const unsigned kb = (unsigned)it * 64u;  // 32 k-elems * 2B
        // stage: each array has 8 chunks of 1KB; 2 chunks per wave per array
#pragma unroll
        for (int ai = 0; ai < NARR; ++ai) {
#pragma unroll
            for (int u = 0; u < 2; ++u) {
                const int f = wave * 2 + u;
                gld_lds16(ws + (size_t)(gb[ai] + (unsigned)f * 16384u + kb),
                          smem + (size_t)(ai * 8 + f) * 512);
            }
        }
        __syncthreads();   // drains vmcnt (global_load_lds) + lgkm

        // B frags: [split][j]
        bf16x8 bfr[NB][4];
#pragma unroll
        for (int s = 0; s < NB; ++s)
#pragma unroll
            for (int j = 0; j < 4; ++j)
                bfr[s][j] = *(const bf16x8*)(smem + (size_t)(s * 8 + wc * 4 + j) * 512 + lane * 8);

#pragma unroll
        for (int i = 0; i < 4; ++i) {
            bf16x8 afr[3];
#pragma unroll
            for (int s = 0; s < 3; ++s)
                afr[s] = *(const bf16x8*)(smem + (size_t)((NB + s) * 8 + wr * 4 + i) * 512 + lane * 8);
#pragma unroll
            for (int p = 0; p < NP; ++p) {
                const int sa = (NP == 3) ? p : PAv[p];
                const int sb = (NP == 3) ? 0 : PBv[p];
#pragma unroll
                for (int j = 0; j < 4; ++j)
                    acc[i][j] = __builtin_amdgcn_mfma_f32_16x16x32_bf16(
                        afr[sa], bfr[sb][j], acc[i][j], 0, 0, 0);
            }
        }
        __syncthreads();   // LDS reads done before next stage
    }

    // epilogue: y = acc*inv + add ; C/D layout: col=lane&15, row=quad*4+r
    const float* bn = (const float*)(ws + bnoff);
    float* outp = (float*)(ws + coff);
    const int quad = lane >> 4;
#pragma unroll
    for (int i = 0; i < 4; ++i) {
        const int ob = o0 + wr * 64 + i * 16 + quad * 4;
        const f32x4 inv = *(const f32x4*)(bn + ob);
        const f32x4 add = *(const f32x4*)(bn + 512 + ob);
#pragma unroll
        for (int j = 0; j < 4; ++j) {
            const int col = v0 + wc * 64 + j * 16 + (lane & 15);
#pragma unroll
            for (int r = 0; r < 4; ++r) {
                const float y = acc[i][j][r] * inv[r] + add[r];
                outp[(size_t)bt * 131072ull + (size_t)(ob + r) * 256ull + col] = y;
            }
        }
    }
}

// ---------------------------------------------------------------------------
// LIF(q), LIF(k), q_sum over head-dim, gate=LIF(q_sum,0.5),
// out = gate * k_spikes written TRANSPOSED as bf16 {0,1} at (t,b,v,d)
// ---------------------------------------------------------------------------
__global__ __launch_bounds__(1024) void k_lif_gate(
    const float* __restrict__ Yq, const float* __restrict__ Yk,
    u16* __restrict__ outbt)
{
    __shared__ float red[4][4][256];  // [dq][t][v]

    const int tid = threadIdx.x;
    const int v  = tid & 255;
    const int dq = tid >> 8;          // 0..3
    const int b  = blockIdx.x >> 2;
    const int h  = blockIdx.x & 3;
    const int c0 = h * 128 + dq * 32;

    float qsum[4] = {0.f, 0.f, 0.f, 0.f};
    unsigned kbits[4] = {0u, 0u, 0u, 0u};

#pragma unroll 4
    for (int dd = 0; dd < 32; ++dd) {
        const size_t base = ((size_t)b * D_ + c0 + dd) * V_ + v;
        float vq = 0.f, vk = 0.f;
#pragma unroll
        for (int t = 0; t < 4; ++t) {
            const float yq = Yq[t * BDV + base];
            vq += (yq - vq) * 0.5f;
            if (vq >= 1.0f) { qsum[t] += 1.0f; vq = 0.f; }
            const float yk = Yk[t * BDV + base];
            vk += (yk - vk) * 0.5f;
            if (vk >= 1.0f) { kbits[t] |= (1u << dd); vk = 0.f; }
        }
    }

#pragma unroll
    for (int t = 0; t < 4; ++t) red[dq][t][v] = qsum[t];
    __syncthreads();

    float g = 0.f;
    float gate[4];
#pragma unroll
    for (int t = 0; t < 4; ++t) {
        const float qs = red[0][t][v] + red[1][t][v] + red[2][t][v] + red[3][t][v];
        g += (qs - g) * 0.5f;
        if (g >= 0.5f) { gate[t] = 1.f; g = 0.f; } else gate[t] = 0.f;
    }

#pragma unroll
    for (int t = 0; t < 4; ++t) {
        const unsigned kb2 = (gate[t] != 0.f) ? kbits[t] : 0u;
        u16* orow = outbt + ((size_t)(t * B_ + b) * V_ + v) * D_ + c0;
#pragma unroll
        for (int c8 = 0; c8 < 4; ++c8) {
            u16x8 w;
#pragma unroll
            for (int e = 0; e < 8; ++e)
                w[e] = ((kb2 >> (c8 * 8 + e)) & 1u) ? (u16)0x3F80 : (u16)0;
            *(u16x8*)(orow + c8 * 8) = w;
        }
    }
}

// ---------------------------------------------------------------------------
// final LIF over Yp -> d_out
// ---------------------------------------------------------------------------
__global__ __launch_bounds__(256) void k_lif_p(
    const float* __restrict__ Yp, float* __restrict__ out2)
{
    const size_t idx = (size_t)blockIdx.x * 256 + threadIdx.x;  // 0..BDV-1
    float v = 0.f;
#pragma unroll
    for (int t = 0; t < 4; ++t) {
        const float y = Yp[t * BDV + idx];
        v += (y - v) * 0.5f;
        float s;
        if (v >= 1.0f) { s = 1.f; v = 0.f; } else s = 0.f;
        out2[t * BDV + idx] = s;
    }
}

// ---------------------------------------------------------------------------
extern "C" void kernel_launch(void* const* d_in, const int* in_sizes, int n_in,
                              void* d_out, int out_size, void* d_ws, size_t ws_size,
                              hipStream_t stream)
{
    const float* x  = (const float*)d_in[0];
    const float* Wq = (const float*)d_in[1];
    const float* qg = (const float*)d_in[2];
    const float* qb = (const float*)d_in[3];
    const float* qm = (const float*)d_in[4];
    const float* qv = (const float*)d_in[5];
    const float* Wk = (const float*)d_in[6];
    const float* kg = (const float*)d_in[7];
    const float* kb = (const float*)d_in[8];
    const float* km = (const float*)d_in[9];
    const float* kv = (const float*)d_in[10];
    const float* Wp = (const float*)d_in[11];
    const float* pg = (const float*)d_in[12];
    const float* pb = (const float*)d_in[13];
    const float* pm = (const float*)d_in[14];
    const float* pv = (const float*)d_in[15];

    char* ws = (char*)d_ws;

    k_prep<<<1024, 256, 0, stream>>>(Wq, Wk, Wp, qg, qb, qm, qv,
                                     kg, kb, km, kv, pg, pb, pm, pv, ws);

    k_split_x<<<dim3(4, 8, 256), 256, 0, stream>>>(
        x, (u16*)(ws + XSH), (u16*)(ws + XSM), (u16*)(ws + XSL));

    const unsigned WQ0 = (unsigned)WSPL;
    const unsigned WK0 = (unsigned)(WSPL + 3ull * 524288ull);
    const unsigned WP0 = (unsigned)(WSPL + 6ull * 524288ull);

    // q = bn(Wq @ x)
    k_gemm<3, 6><<<dim3(2, 4, 256), 256, 49152, stream>>>(
        ws, (unsigned)XSH, (unsigned)XSM, (unsigned)XSL,
        WQ0, WQ0 + 524288u, WQ0 + 1048576u,
        (unsigned)BNOF, (unsigned)YQOFF);

    // k = bn(Wk @ x)
    k_gemm<3, 6><<<dim3(2, 4, 256), 256, 49152, stream>>>(
        ws, (unsigned)XSH, (unsigned)XSM, (unsigned)XSL,
        WK0, WK0 + 524288u, WK0 + 1048576u,
        (unsigned)BNOF + 4096u, (unsigned)YKOFF);

    // LIF + gate -> binary bf16 (t,b,v,d)
    k_lif_gate<<<256, 1024, 0, stream>>>(
        (const float*)(ws + YQOFF), (const float*)(ws + YKOFF), (u16*)(ws + OUTBT));

    // Yp = bn(Wp @ out)   (binary B: single split, 3 passes)
    k_gemm<1, 3><<<dim3(2, 4, 256), 256, 32768, stream>>>(
        ws, (unsigned)OUTBT, (unsigned)OUTBT, (unsigned)OUTBT,
        WP0, WP0 + 524288u, WP0 + 1048576u,
        (unsigned)BNOF + 8192u, (unsigned)YPOFF);

    // final LIF -> d_out
    k_lif_p<<<32768, 256, 0, stream>>>((const float*)(ws + YPOFF), (float*)d_out);
}

// Round 4
// 812.001 us; speedup vs baseline: 2.2726x; 1.2159x over previous
//
#include <hip/hip_runtime.h>

#define T_ 4
#define B_ 64
#define D_ 512
#define V_ 256

// ---- workspace byte offsets ----
#define XSH   0ull             // x^T split hi (t*64+b, v, d) bf16, 67.1 MB
#define XSM   67108864ull
#define XSL   134217728ull
#define OUTBT 201326592ull     // gate*k spikes, (t*64+b, v, d) bf16 {0,1}, 67.1 MB
#define WT    268435456ull     // frag-tiled W splits: (mat*3+s) arrays of 512KB
#define BNOF  273154048ull     // 6x512 floats

typedef unsigned short u16;
typedef __attribute__((ext_vector_type(8))) __bf16 bf16x8;
typedef __attribute__((ext_vector_type(4))) float f32x4;
typedef __attribute__((ext_vector_type(8))) unsigned short u16x8;
typedef __attribute__((ext_vector_type(4))) unsigned short u16x4;

__device__ __forceinline__ u16 f2bf(float f) {
    unsigned u = __float_as_uint(f);
    return (u16)((u + 0x7FFFu + ((u >> 16) & 1u)) >> 16);
}
__device__ __forceinline__ float bf2f(u16 h) {
    return __uint_as_float(((unsigned)h) << 16);
}

// async global->LDS, 16B/lane; LDS dest = wave-uniform base + lane*16
__device__ __forceinline__ void gld_lds16(const void* g, void* l) {
    __builtin_amdgcn_global_load_lds(
        (const __attribute__((address_space(1))) unsigned int*)(unsigned long long)g,
        (__attribute__((address_space(3))) unsigned int*)(unsigned long long)l,
        16, 0, 0);
}

// ---------------------------------------------------------------------------
// prep: W splits in FRAG-LINEAR layout + BN constants.
// Array (mat,s): idx = ((head*16+it)*8+ip)*512 + lane*8 + e  holds
//   W[head*128 + ip*16 + (lane&15)][it*32 + (lane>>4)*8 + e]  (split s)
// => a wave's A-frag load is one coalesced 1KB global_load_dwordx4.
// ---------------------------------------------------------------------------
__global__ __launch_bounds__(256) void k_prep2(
    const float* __restrict__ Wq, const float* __restrict__ Wk, const float* __restrict__ Wp,
    const float* __restrict__ qg, const float* __restrict__ qb,
    const float* __restrict__ qm, const float* __restrict__ qv,
    const float* __restrict__ kg, const float* __restrict__ kb,
    const float* __restrict__ km, const float* __restrict__ kv,
    const float* __restrict__ pg, const float* __restrict__ pb,
    const float* __restrict__ pm, const float* __restrict__ pv,
    char* __restrict__ ws)
{
    const int g = blockIdx.x * 256 + threadIdx.x;   // [0, 98304)
    const int mat = g >> 15;
    const int r = g & 32767;
    const int lane = r & 63;
    const int q = r >> 6;            // 0..511 = (head*16+it)*8+ip
    const int ip = q & 7;
    const int q2 = q >> 3;
    const int it = q2 & 15;
    const int head = q2 >> 4;
    const int row = head * 128 + ip * 16 + (lane & 15);
    const int kcol = it * 32 + (lane >> 4) * 8;
    const float* W = (mat == 0) ? Wq : (mat == 1 ? Wk : Wp);

    u16x8 h8, m8, l8;
#pragma unroll
    for (int e = 0; e < 8; ++e) {
        const float f = W[row * 512 + kcol + e];
        const u16 h = f2bf(f);          const float fh = bf2f(h);
        const u16 m = f2bf(f - fh);     const float fm = bf2f(m);
        const u16 l = f2bf(f - fh - fm);
        h8[e] = h; m8[e] = m; l8[e] = l;
    }
    u16* wt = (u16*)(ws + WT);
    const size_t o = (size_t)r * 8;
    *(u16x8*)(wt + (size_t)(mat * 3 + 0) * 262144 + o) = h8;
    *(u16x8*)(wt + (size_t)(mat * 3 + 1) * 262144 + o) = m8;
    *(u16x8*)(wt + (size_t)(mat * 3 + 2) * 262144 + o) = l8;

    if (g < 512) {
        float* bn = (float*)(ws + BNOF);
        float iv;
        iv = qg[g] * (1.0f / sqrtf(qv[g] + 1e-5f)); bn[g]        = iv; bn[512  + g] = qb[g] - qm[g] * iv;
        iv = kg[g] * (1.0f / sqrtf(kv[g] + 1e-5f)); bn[1024 + g] = iv; bn[1536 + g] = kb[g] - km[g] * iv;
        iv = pg[g] * (1.0f / sqrtf(pv[g] + 1e-5f)); bn[2048 + g] = iv; bn[2560 + g] = pb[g] - pm[g] * iv;
    }
}

// ---------------------------------------------------------------------------
// split_x: x (t,b,d,v) fp32 -> transposed 3-way bf16 splits (t*64+b, v, d)
// ---------------------------------------------------------------------------
__global__ __launch_bounds__(256) void k_split_x(
    const float* __restrict__ x,
    u16* __restrict__ xh, u16* __restrict__ xm, u16* __restrict__ xl)
{
    __shared__ float tile[64][65];
    const int bt = blockIdx.z;
    const int d0 = blockIdx.y * 64;
    const int v0 = blockIdx.x * 64;
    const int c  = threadIdx.x & 63;
    const int r4 = threadIdx.x >> 6;

    const float* src = x + ((size_t)bt * D_ + d0) * V_ + v0;
#pragma unroll
    for (int i = 0; i < 16; ++i) {
        const int row = i * 4 + r4;
        tile[row][c] = src[(size_t)row * V_ + c];
    }
    __syncthreads();
#pragma unroll
    for (int i = 0; i < 16; ++i) {
        const int vr = i * 4 + r4;
        const float f = tile[c][vr];
        const u16 h = f2bf(f);          const float fh = bf2f(h);
        const u16 m = f2bf(f - fh);     const float fm = bf2f(m);
        const u16 l = f2bf(f - fh - fm);
        const size_t o = ((size_t)bt * V_ + v0 + vr) * D_ + d0 + c;
        xh[o] = h; xm[o] = m; xl[o] = l;
    }
}

// ---------------------------------------------------------------------------
// Fused q+k: per block = (b, head, v-tile 128), both GEMM phases over all 4 t.
// Phase 0 (Wq): GEMM -> BN -> LIF -> q spikes -> head-sum -> gate LIF (LDS).
// Phase 1 (Wk): GEMM -> BN -> LIF -> k spikes -> gate -> binary bf16 out^T.
// A-frags direct from global (frag-linear, L2-hot); only B staged in LDS.
// ---------------------------------------------------------------------------
__global__ __launch_bounds__(256, 2) void k_qk_fused(char* __restrict__ ws)
{
    __shared__ u16 stg[17408];       // B staging (3x4096 u16) ∪ out tile (128x136)
    __shared__ float qs[256];        // [wr][col] partial head sums
    __shared__ float gatef[512];     // [t][col]

    const int tid  = threadIdx.x;
    const int lane = tid & 63;
    const int wave = tid >> 6;
    const int wr = wave >> 1, wc = wave & 1;
    const int quad = lane >> 4;
    const int l15  = lane & 15;

    const unsigned bid  = blockIdx.x;
    const unsigned rr   = bid >> 3;
    const unsigned head = rr & 3;
    const unsigned unit = (bid & 7) + 8u * (rr >> 2);   // same-XCD groups share (b,vt)
    const unsigned b    = unit >> 1;
    const unsigned vt   = unit & 1;
    const unsigned v0   = vt * 128u;
    const unsigned o0h  = head * 128u;

    // B per-lane byte base (t=0, chunk f=0, it=0)
    const unsigned rbase = (b * 256u + v0 + (unsigned)l15) * 1024u + (unsigned)(lane >> 4) * 16u;
    const unsigned xsb[3] = {(unsigned)XSH, (unsigned)XSM, (unsigned)XSL};

    const int PA[6] = {0, 0, 1, 1, 0, 2};
    const int PB[6] = {0, 1, 0, 1, 2, 0};

    float gstate = 0.f;   // gate LIF state (used by tid<128)

    for (int ph = 0; ph < 2; ++ph) {
        // A frag per-lane byte bases (3 splits of Wq or Wk)
        unsigned ab[3];
#pragma unroll
        for (int s = 0; s < 3; ++s)
            ab[s] = (unsigned)WT + ((unsigned)ph * 3u + (unsigned)s) * 524288u
                  + head * 131072u + (unsigned)wr * 4096u + (unsigned)lane * 16u;
        const float* bn = (const float*)(ws + BNOF + (size_t)ph * 4096);

        f32x4 st[4][4];   // LIF membrane state (vq / vk)
#pragma unroll
        for (int i = 0; i < 4; ++i)
#pragma unroll
            for (int j = 0; j < 4; ++j) st[i][j] = (f32x4){0.f, 0.f, 0.f, 0.f};

        for (int t = 0; t < 4; ++t) {
            f32x4 acc[4][4];
#pragma unroll
            for (int i = 0; i < 4; ++i)
#pragma unroll
                for (int j = 0; j < 4; ++j) acc[i][j] = (f32x4){0.f, 0.f, 0.f, 0.f};

            const unsigned tb = (unsigned)t * 16777216u + rbase;

            for (int it = 0; it < 16; ++it) {
                const unsigned ko = (unsigned)it * 64u;
                // stage B: 24 chunks, 6 per wave
#pragma unroll
                for (int u = 0; u < 6; ++u) {
                    const int fg = wave * 6 + u;
                    const int ai = fg >> 3, f = fg & 7;
                    gld_lds16(ws + (size_t)(xsb[ai] + tb + (unsigned)f * 16384u + ko),
                              stg + (size_t)(ai * 8 + f) * 512);
                }
                __syncthreads();
                bf16x8 bfr[3][4];
#pragma unroll
                for (int s = 0; s < 3; ++s)
#pragma unroll
                    for (int j = 0; j < 4; ++j)
                        bfr[s][j] = *(const bf16x8*)(stg + (size_t)(s * 8 + wc * 4 + j) * 512 + lane * 8);

#pragma unroll
                for (int ih = 0; ih < 2; ++ih) {
                    bf16x8 afr[3][2];
#pragma unroll
                    for (int s = 0; s < 3; ++s)
#pragma unroll
                        for (int i2 = 0; i2 < 2; ++i2)
                            afr[s][i2] = *(const bf16x8*)(ws + (size_t)(ab[s]
                                          + (unsigned)it * 8192u + (unsigned)(ih * 2 + i2) * 1024u));
#pragma unroll
                    for (int i2 = 0; i2 < 2; ++i2) {
                        const int i = ih * 2 + i2;
#pragma unroll
                        for (int p = 0; p < 6; ++p)
#pragma unroll
                            for (int j = 0; j < 4; ++j)
                                acc[i][j] = __builtin_amdgcn_mfma_f32_16x16x32_bf16(
                                    afr[PA[p]][i2], bfr[PB[p]][j], acc[i][j], 0, 0, 0);
                    }
                }
                __syncthreads();
            }

            if (ph == 0) {
                // ---- phase Q epilogue: BN + LIF + per-column spike sums ----
                float qp[4] = {0.f, 0.f, 0.f, 0.f};
#pragma unroll
                for (int i = 0; i < 4; ++i) {
                    const int ob = (int)o0h + wr * 64 + i * 16 + quad * 4;
                    const f32x4 inv = *(const f32x4*)(bn + ob);
                    const f32x4 add = *(const f32x4*)(bn + 512 + ob);
#pragma unroll
                    for (int j = 0; j < 4; ++j)
#pragma unroll
                        for (int r = 0; r < 4; ++r) {
                            const float y = acc[i][j][r] * inv[r] + add[r];
                            float v = (st[i][j][r] + y) * 0.5f;
                            const float s = (v >= 1.0f) ? 1.f : 0.f;
                            st[i][j][r] = (v >= 1.0f) ? 0.f : v;
                            qp[j] += s;
                        }
                }
#pragma unroll
                for (int j = 0; j < 4; ++j) {
                    qp[j] += __shfl_xor(qp[j], 16, 64);
                    qp[j] += __shfl_xor(qp[j], 32, 64);
                }
                if (quad == 0) {
#pragma unroll
                    for (int j = 0; j < 4; ++j)
                        qs[wr * 128 + wc * 64 + j * 16 + l15] = qp[j];
                }
                __syncthreads();
                if (tid < 128) {
                    const float qsum = qs[tid] + qs[128 + tid];
                    gstate = (gstate + qsum) * 0.5f;
                    const float gt = (gstate >= 0.5f) ? 1.f : 0.f;
                    gstate = (gstate >= 0.5f) ? 0.f : gstate;
                    gatef[t * 128 + tid] = gt;
                }
                __syncthreads();
            } else {
                // ---- phase K epilogue: BN + LIF + gate -> out^T tile ----
#pragma unroll
                for (int i = 0; i < 4; ++i) {
                    const int ob = (int)o0h + wr * 64 + i * 16 + quad * 4;
                    const f32x4 inv = *(const f32x4*)(bn + ob);
                    const f32x4 add = *(const f32x4*)(bn + 512 + ob);
#pragma unroll
                    for (int j = 0; j < 4; ++j) {
                        const int col = wc * 64 + j * 16 + l15;
                        const float gt = gatef[t * 128 + col];
                        u16x4 w;
#pragma unroll
                        for (int r = 0; r < 4; ++r) {
                            const float y = acc[i][j][r] * inv[r] + add[r];
                            float v = (st[i][j][r] + y) * 0.5f;
                            const float s = (v >= 1.0f) ? 1.f : 0.f;
                            st[i][j][r] = (v >= 1.0f) ? 0.f : v;
                            w[r] = (s * gt != 0.f) ? (u16)0x3F80 : (u16)0;
                        }
                        *(u16x4*)(&stg[col * 136 + wr * 64 + i * 16 + quad * 4]) = w;
                    }
                }
                __syncthreads();
                // coalesced store of the (v,d) tile
#pragma unroll
                for (int cc = 0; cc < 8; ++cc) {
                    const int c = cc * 256 + tid;
                    const int vv = c >> 4, ch = c & 15;
                    const float4 f4 = *(const float4*)(stg + (size_t)vv * 136 + ch * 8);
                    *(float4*)(ws + OUTBT
                               + ((size_t)((t * 64 + b) * 256 + v0 + vv) * 512 + o0h) * 2
                               + ch * 16) = f4;
                }
                __syncthreads();
            }
        }
    }
}

// ---------------------------------------------------------------------------
// Fused p: out2 = LIF(bn_p(Wp @ out)). K-outer, all 4 t accumulated in-block,
// LIF scan in epilogue, direct write to d_out. B binary bf16 (1 split, 3 passes).
// ---------------------------------------------------------------------------
__global__ __launch_bounds__(256, 2) void k_p_fused(char* __restrict__ ws,
                                                    float* __restrict__ out2)
{
    __shared__ u16 stg[8192];    // 4 t-arrays x 4 chunks x 512

    const int tid  = threadIdx.x;
    const int lane = tid & 63;
    const int wave = tid >> 6;
    const int wr = wave >> 1, wc = wave & 1;
    const int quad = lane >> 4;
    const int l15  = lane & 15;

    const unsigned bid  = blockIdx.x;
    const unsigned rr   = bid >> 3;
    const unsigned ot   = rr & 3;
    const unsigned unit = (bid & 7) + 8u * (rr >> 2);   // 0..255
    const unsigned b    = unit >> 2;
    const unsigned vt   = unit & 3;
    const unsigned v0   = vt * 64u;
    const unsigned o0   = ot * 128u;

    const unsigned rbase = (unsigned)OUTBT + (b * 256u + v0 + (unsigned)l15) * 1024u
                         + (unsigned)(lane >> 4) * 16u;
    unsigned ab[3];
#pragma unroll
    for (int s = 0; s < 3; ++s)
        ab[s] = (unsigned)WT + (6u + (unsigned)s) * 524288u
              + ot * 131072u + (unsigned)wr * 4096u + (unsigned)lane * 16u;

    f32x4 acc[4][4][2];   // [t][i][j]
#pragma unroll
    for (int t = 0; t < 4; ++t)
#pragma unroll
        for (int i = 0; i < 4; ++i)
#pragma unroll
            for (int j = 0; j < 2; ++j) acc[t][i][j] = (f32x4){0.f, 0.f, 0.f, 0.f};

    for (int it = 0; it < 16; ++it) {
        const unsigned ko = (unsigned)it * 64u;
#pragma unroll
        for (int u = 0; u < 4; ++u) {
            const int fg = wave * 4 + u;
            const int ai = fg >> 2, f = fg & 3;
            gld_lds16(ws + (size_t)(rbase + (unsigned)ai * 16777216u + (unsigned)f * 16384u + ko),
                      stg + (size_t)(ai * 4 + f) * 512);
        }
        __syncthreads();
        bf16x8 bfr[4][2];
#pragma unroll
        for (int tt = 0; tt < 4; ++tt)
#pragma unroll
            for (int j = 0; j < 2; ++j)
                bfr[tt][j] = *(const bf16x8*)(stg + (size_t)(tt * 4 + wc * 2 + j) * 512 + lane * 8);

#pragma unroll
        for (int ih = 0; ih < 2; ++ih) {
            bf16x8 afr[3][2];
#pragma unroll
            for (int s = 0; s < 3; ++s)
#pragma unroll
                for (int i2 = 0; i2 < 2; ++i2)
                    afr[s][i2] = *(const bf16x8*)(ws + (size_t)(ab[s]
                                  + (unsigned)it * 8192u + (unsigned)(ih * 2 + i2) * 1024u));
#pragma unroll
            for (int i2 = 0; i2 < 2; ++i2) {
                const int i = ih * 2 + i2;
#pragma unroll
                for (int tt = 0; tt < 4; ++tt)
#pragma unroll
                    for (int p = 0; p < 3; ++p)
#pragma unroll
                        for (int j = 0; j < 2; ++j)
                            acc[tt][i][j] = __builtin_amdgcn_mfma_f32_16x16x32_bf16(
                                afr[p][i2], bfr[tt][j], acc[tt][i][j], 0, 0, 0);
            }
        }
        __syncthreads();
    }

    // epilogue: BN + LIF over t, write spikes (T,B,D,V) fp32
    const float* bn = (const float*)(ws + BNOF + 8192);
#pragma unroll
    for (int i = 0; i < 4; ++i) {
        const int ob = (int)o0 + wr * 64 + i * 16 + quad * 4;
        const f32x4 inv = *(const f32x4*)(bn + ob);
        const f32x4 add = *(const f32x4*)(bn + 512 + ob);
#pragma unroll
        for (int j = 0; j < 2; ++j) {
            const int col = (int)v0 + wc * 32 + j * 16 + l15;
#pragma unroll
            for (int r = 0; r < 4; ++r) {
                float v = 0.f;
#pragma unroll
                for (int tt = 0; tt < 4; ++tt) {
                    const float y = acc[tt][i][j][r] * inv[r] + add[r];
                    v = (v + y) * 0.5f;
                    const float s = (v >= 1.0f) ? 1.f : 0.f;
                    v = (v >= 1.0f) ? 0.f : v;
                    out2[((size_t)(tt * 64 + b) * 512 + ob + r) * 256 + col] = s;
                }
            }
        }
    }
}

// ---------------------------------------------------------------------------
extern "C" void kernel_launch(void* const* d_in, const int* in_sizes, int n_in,
                              void* d_out, int out_size, void* d_ws, size_t ws_size,
                              hipStream_t stream)
{
    const float* x  = (const float*)d_in[0];
    const float* Wq = (const float*)d_in[1];
    const float* qg = (const float*)d_in[2];
    const float* qb = (const float*)d_in[3];
    const float* qm = (const float*)d_in[4];
    const float* qv = (const float*)d_in[5];
    const float* Wk = (const float*)d_in[6];
    const float* kg = (const float*)d_in[7];
    const float* kb = (const float*)d_in[8];
    const float* km = (const float*)d_in[9];
    const float* kv = (const float*)d_in[10];
    const float* Wp = (const float*)d_in[11];
    const float* pg = (const float*)d_in[12];
    const float* pb = (const float*)d_in[13];
    const float* pm = (const float*)d_in[14];
    const float* pv = (const float*)d_in[15];

    char* ws = (char*)d_ws;

    k_prep2<<<384, 256, 0, stream>>>(Wq, Wk, Wp, qg, qb, qm, qv,
                                     kg, kb, km, kv, pg, pb, pm, pv, ws);

    k_split_x<<<dim3(4, 8, 256), 256, 0, stream>>>(
        x, (u16*)(ws + XSH), (u16*)(ws + XSM), (u16*)(ws + XSL));

    k_qk_fused<<<512, 256, 0, stream>>>(ws);

    k_p_fused<<<1024, 256, 0, stream>>>(ws, (float*)d_out);
}